// Round 3
// baseline (2042.520 us; speedup 1.0000x reference)
//
#include <hip/hip_runtime.h>
#include <cfloat>

#define N_TOK   32768
#define DIM     64
#define K_CODES 8192
#define KP      8                    // K partitions (argmin split)
#define KPC     (K_CODES / KP)       // 1024 codes per partition
#define TBLK    (N_TOK / 256)        // 128 token blocks

#define IDX_OFF  (N_TOK * DIM)
#define LOSS_OFF (N_TOK * DIM + N_TOK)

// workspace layout (float units)
#define WS_ESQ    0
#define WS_BEST   (WS_ESQ + K_CODES)          // KP * N_TOK floats
#define WS_PIDX   (WS_BEST + KP * N_TOK)      // KP * N_TOK ints
#define WS_PART   (WS_PIDX + KP * N_TOK)      // 128 floats

// Launder a wave-uniform pointer through readfirstlane so the backend keeps
// it (and all constant-offset loads off it) in SGPRs -> s_load_dwordx8/16.
__device__ inline const float* uniform_ptr(const float* p) {
    unsigned long long u = (unsigned long long)p;
    unsigned lo = __builtin_amdgcn_readfirstlane((unsigned)u);
    unsigned hi = __builtin_amdgcn_readfirstlane((unsigned)(u >> 32));
    return (const float*)(((unsigned long long)hi << 32) | lo);
}

// ---------------------------------------------------------------------------
// e_sq[k] = numpy-pairwise sum of squares of embedding row k (bitwise np order)
// ---------------------------------------------------------------------------
__global__ __launch_bounds__(256) void esq_kernel(const float* __restrict__ emb,
                                                  float* __restrict__ esq) {
#pragma clang fp contract(off)
    const int tid = threadIdx.x;
    const int q = tid & 7;
    const int code = blockIdx.x * 32 + (tid >> 3);
    const float* row = emb + code * DIM;
    float x = row[q];
    float r = x * x;
#pragma unroll
    for (int m = 1; m < 8; ++m) {
        float y = row[q + 8 * m];
        float sq = y * y;
        r = r + sq;
    }
    r = r + __shfl_xor(r, 1, 64);
    r = r + __shfl_xor(r, 2, 64);
    r = r + __shfl_xor(r, 4, 64);
    if (q == 0) esq[code] = r;
}

// ---------------------------------------------------------------------------
// Distance scan: thread = 1 token (z in VGPRs), e rows via scalar loads.
// Block b: tokens [(b&127)*256, ...), codes [kp*1024, (kp+1)*1024), kp=b>>7.
// Inner chain: acc = z0*e0; acc = fmaf(zj, ej, acc) j=1..63  (bitwise = BLAS)
// d = fl( fl(zsq+esq) - 2*dot );  strict < keeps earliest index in-partition.
// ---------------------------------------------------------------------------
__global__ __launch_bounds__(256, 4) void vq_scan(const float* __restrict__ hid,
                                                  const float* __restrict__ emb,
                                                  const float* __restrict__ esq,
                                                  float* __restrict__ pbest,
                                                  int* __restrict__ pidx) {
#pragma clang fp contract(off)
    const int tid = threadIdx.x;
    const int bid = blockIdx.x;
    const int kp  = bid >> 7;
    const int tok = ((bid & (TBLK - 1)) << 8) | tid;
    const int k0  = kp * KPC;

    // ---- z[64] into registers (one-time) ----
    float z[DIM];
    {
        const float4* h4 = reinterpret_cast<const float4*>(hid + (size_t)tok * DIM);
        float4* zp = reinterpret_cast<float4*>(z);
#pragma unroll
        for (int i = 0; i < 16; ++i) zp[i] = h4[i];
    }

    // ---- z_sq, numpy pairwise order ----
    float r[8];
#pragma unroll
    for (int q = 0; q < 8; ++q) {
        float x = z[q];
        r[q] = x * x;
#pragma unroll
        for (int m = 1; m < 8; ++m) {
            float y = z[q + 8 * m];
            float sq = y * y;
            r[q] = r[q] + sq;
        }
    }
    const float zsq = ((r[0] + r[1]) + (r[2] + r[3])) + ((r[4] + r[5]) + (r[6] + r[7]));

    // wave-uniform scalar sources
    const float* __restrict__ eu  = uniform_ptr(emb + (size_t)k0 * DIM);
    const float* __restrict__ squ = uniform_ptr(esq + k0);

    float best = FLT_MAX;
    int   bi   = 0;

#pragma unroll 2
    for (int kk = 0; kk < KPC; ++kk) {
        const float* ek = eu + kk * DIM;   // uniform -> s_load batches
        float acc = z[0] * ek[0];
#pragma unroll
        for (int j = 1; j < DIM; ++j)
            acc = fmaf(z[j], ek[j], acc);
        const float s = zsq + squ[kk];
        const float d = fmaf(-2.0f, acc, s);
        const int k = k0 + kk;
        if (d < best) { best = d; bi = k; }
    }

    pbest[kp * N_TOK + tok] = best;
    pidx [kp * N_TOK + tok] = bi;
}

// ---------------------------------------------------------------------------
// Merge partitions (ascending p => ascending k-ranges; strict < keeps the
// earliest partition on ties == np.argmin first-occurrence), then outputs.
// ---------------------------------------------------------------------------
__global__ __launch_bounds__(256) void vq_finish(const float* __restrict__ hid,
                                                 const float* __restrict__ emb,
                                                 const float* __restrict__ pbest,
                                                 const int* __restrict__ pidx,
                                                 float* __restrict__ out_zq,
                                                 float* __restrict__ out_idx,
                                                 float* __restrict__ partials) {
#pragma clang fp contract(off)
    __shared__ float lred[4];
    const int tid = threadIdx.x;
    const int t = blockIdx.x * 256 + tid;

    float best = pbest[t];
    int   bi   = pidx[t];
#pragma unroll
    for (int p = 1; p < KP; ++p) {
        const float b = pbest[p * N_TOK + t];
        const int   i = pidx [p * N_TOK + t];
        if (b < best) { best = b; bi = i; }
    }
    out_idx[t] = (float)bi;

    const float4* q4 = reinterpret_cast<const float4*>(emb + (size_t)bi * DIM);
    const float4* h4 = reinterpret_cast<const float4*>(hid + (size_t)t * DIM);
    float4* o4 = reinterpret_cast<float4*>(out_zq + (size_t)t * DIM);
    float lsum = 0.f;
#pragma unroll
    for (int i = 0; i < 16; ++i) {
        const float4 q = q4[i];
        const float4 h = h4[i];
        float4 zq;
        float dx;
        dx = q.x - h.x; zq.x = h.x + dx; lsum += dx * dx;
        dx = q.y - h.y; zq.y = h.y + dx; lsum += dx * dx;
        dx = q.z - h.z; zq.z = h.z + dx; lsum += dx * dx;
        dx = q.w - h.w; zq.w = h.w + dx; lsum += dx * dx;
        o4[i] = zq;
    }

#pragma unroll
    for (int off = 32; off >= 1; off >>= 1) lsum += __shfl_xor(lsum, off, 64);
    const int wid = tid >> 6;
    if ((tid & 63) == 0) lred[wid] = lsum;
    __syncthreads();
    if (tid == 0) partials[blockIdx.x] = (lred[0] + lred[1]) + (lred[2] + lred[3]);
}

// ---------------------------------------------------------------------------
// Final loss over 128 block partials
// ---------------------------------------------------------------------------
__global__ __launch_bounds__(128) void loss_kernel(const float* __restrict__ partials,
                                                   float* __restrict__ out_loss) {
#pragma clang fp contract(off)
    __shared__ float s[128];
    const int t = threadIdx.x;
    s[t] = partials[t];
    __syncthreads();
    for (int off = 64; off >= 1; off >>= 1) {
        if (t < off) s[t] = s[t] + s[t + off];
        __syncthreads();
    }
    if (t == 0) {
        const float m = s[0] * (1.0f / 2097152.0f);  // exact: /2^21
        out_loss[0] = m + 0.25f * m;
    }
}

extern "C" void kernel_launch(void* const* d_in, const int* in_sizes, int n_in,
                              void* d_out, int out_size, void* d_ws, size_t ws_size,
                              hipStream_t stream) {
    const float* hid = (const float*)d_in[0];
    const float* emb = (const float*)d_in[1];
    float* out = (float*)d_out;
    float* ws  = (float*)d_ws;
    float* esq   = ws + WS_ESQ;
    float* pbest = ws + WS_BEST;
    int*   pidx  = (int*)(ws + WS_PIDX);
    float* parts = ws + WS_PART;

    esq_kernel<<<K_CODES / 32, 256, 0, stream>>>(emb, esq);
    vq_scan<<<TBLK * KP, 256, 0, stream>>>(hid, emb, esq, pbest, pidx);
    vq_finish<<<N_TOK / 256, 256, 0, stream>>>(hid, emb, pbest, pidx,
                                               out, out + IDX_OFF, parts);
    loss_kernel<<<1, 128, 0, stream>>>(parts, out + LOSS_OFF);
}

// Round 4
// 664.522 us; speedup vs baseline: 3.0737x; 3.0737x over previous
//
#include <hip/hip_runtime.h>
#include <cfloat>

#define N_TOK   32768
#define DIM     64
#define K_CODES 8192
#define KP      8                    // K partitions (argmin split, merged with tie-break)
#define KPC     (K_CODES / KP)       // 1024 codes per partition
#define CB      256                  // codes per LDS chunk
#define NCH     (KPC / CB)           // 4 chunks per block
#define TB      256                  // tokens per block
#define TBLK    (N_TOK / TB)         // 128 token blocks

#define IDX_OFF  (N_TOK * DIM)
#define LOSS_OFF (N_TOK * DIM + N_TOK)

// workspace layout (float units) — same as R3 (proven)
#define WS_ESQ    0
#define WS_BEST   (WS_ESQ + K_CODES)          // KP * N_TOK floats
#define WS_PIDX   (WS_BEST + KP * N_TOK)      // KP * N_TOK ints
#define WS_PART   (WS_PIDX + KP * N_TOK)      // 128 floats

// ---------------------------------------------------------------------------
// e_sq[k] = numpy-pairwise sum of squares of embedding row k (bitwise np order)
// ---------------------------------------------------------------------------
__global__ __launch_bounds__(256) void esq_kernel(const float* __restrict__ emb,
                                                  float* __restrict__ esq) {
#pragma clang fp contract(off)
    const int tid = threadIdx.x;
    const int q = tid & 7;
    const int code = blockIdx.x * 32 + (tid >> 3);
    const float* row = emb + code * DIM;
    float x = row[q];
    float r = x * x;
#pragma unroll
    for (int m = 1; m < 8; ++m) {
        float y = row[q + 8 * m];
        float sq = y * y;
        r = r + sq;
    }
    r = r + __shfl_xor(r, 1, 64);
    r = r + __shfl_xor(r, 2, 64);
    r = r + __shfl_xor(r, 4, 64);
    if (q == 0) esq[code] = r;
}

// ---------------------------------------------------------------------------
// Distance scan: block = 256 tokens x 1024-code partition (4 chunks of 256).
// 256 threads; thread tile = 16 tokens x 16 codes; acc in 256 VGPRs.
// Per j: 4 z-quads + 4 e-quads (8 ds_read_b128) feed 256 FMAs -> VALU-bound.
// Codes per thread (ascending): {64q + 4tx + b}, q=0..3, b=0..3.
// ---------------------------------------------------------------------------
__global__ __launch_bounds__(256, 1) void vq_scan(const float* __restrict__ hid,
                                                  const float* __restrict__ emb,
                                                  const float* __restrict__ esq,
                                                  float* __restrict__ pbest,
                                                  int* __restrict__ pidx) {
#pragma clang fp contract(off)
    __shared__ float zT[DIM][TB];     // zT[j][t]  (stride 256: 2-way banks, free)
    __shared__ float eT[DIM][CB];     // eT[j][c]
    __shared__ float zsq_s[TB];

    const int tid = threadIdx.x;
    const int bid = blockIdx.x;
    const int kp  = bid >> 7;                 // partition
    const int tb  = (bid & (TBLK - 1)) * TB;  // token base
    const int k0  = kp * KPC;

    const int tx = tid & 15;        // code lane
    const int ty = tid >> 4;        // token group
    const int tg = ty * 16;         // 16 tokens per thread

    // ---- stage z tile (thread = one token row) + z_sq (numpy pairwise) ----
    {
        const float4* h4 = reinterpret_cast<const float4*>(hid + (size_t)(tb + tid) * DIM);
        float4 v[16];
#pragma unroll
        for (int i = 0; i < 16; ++i) v[i] = h4[i];
#pragma unroll
        for (int i = 0; i < 16; ++i) {
            const int j = 4 * i;
            zT[j + 0][tid] = v[i].x;
            zT[j + 1][tid] = v[i].y;
            zT[j + 2][tid] = v[i].z;
            zT[j + 3][tid] = v[i].w;
        }
        const float* zr = reinterpret_cast<const float*>(v);
        float r[8];
#pragma unroll
        for (int q = 0; q < 8; ++q) {
            float x = zr[q];
            r[q] = x * x;
#pragma unroll
            for (int m = 1; m < 8; ++m) {
                float y = zr[q + 8 * m];
                float sq = y * y;
                r[q] = r[q] + sq;
            }
        }
        zsq_s[tid] = ((r[0] + r[1]) + (r[2] + r[3])) + ((r[4] + r[5]) + (r[6] + r[7]));
    }
    __syncthreads();

    float zsq_r[16];
#pragma unroll
    for (int a = 0; a < 4; ++a)
        *reinterpret_cast<float4*>(&zsq_r[4 * a]) =
            *reinterpret_cast<const float4*>(&zsq_s[tg + 4 * a]);

    float best[16];
    int   bidx[16];
#pragma unroll
    for (int a = 0; a < 16; ++a) { best[a] = FLT_MAX; bidx[a] = 0; }

    for (int ch = 0; ch < NCH; ++ch) {
        if (ch) __syncthreads();            // eT overwrite guard
        // ---- stage e chunk (thread = one code row) ----
        {
            const float4* e4 = reinterpret_cast<const float4*>(
                emb + (size_t)(k0 + ch * CB + tid) * DIM);
            float4 v[16];
#pragma unroll
            for (int i = 0; i < 16; ++i) v[i] = e4[i];
#pragma unroll
            for (int i = 0; i < 16; ++i) {
                const int j = 4 * i;
                eT[j + 0][tid] = v[i].x;
                eT[j + 1][tid] = v[i].y;
                eT[j + 2][tid] = v[i].z;
                eT[j + 3][tid] = v[i].w;
            }
        }
        __syncthreads();

        const int kb = k0 + ch * CB;
        float4 es[4];
#pragma unroll
        for (int q = 0; q < 4; ++q)
            es[q] = *reinterpret_cast<const float4*>(esq + kb + 64 * q + 4 * tx);

        float acc[16][16];

        // ---- j = 0 peeled: acc = z0 * e0 (bitwise head of BLAS chain) ----
        {
            float za[16], eb[16];
#pragma unroll
            for (int a = 0; a < 4; ++a)
                *reinterpret_cast<float4*>(&za[4 * a]) =
                    *reinterpret_cast<const float4*>(&zT[0][tg + 4 * a]);
#pragma unroll
            for (int q = 0; q < 4; ++q)
                *reinterpret_cast<float4*>(&eb[4 * q]) =
                    *reinterpret_cast<const float4*>(&eT[0][4 * tx + 64 * q]);
#pragma unroll
            for (int a = 0; a < 16; ++a)
#pragma unroll
                for (int c = 0; c < 16; ++c)
                    acc[a][c] = za[a] * eb[c];
        }

        // ---- j = 1..63: sequential FMA chains ----
#pragma unroll 7
        for (int j = 1; j < DIM; ++j) {
            float za[16], eb[16];
#pragma unroll
            for (int a = 0; a < 4; ++a)
                *reinterpret_cast<float4*>(&za[4 * a]) =
                    *reinterpret_cast<const float4*>(&zT[j][tg + 4 * a]);
#pragma unroll
            for (int q = 0; q < 4; ++q)
                *reinterpret_cast<float4*>(&eb[4 * q]) =
                    *reinterpret_cast<const float4*>(&eT[j][4 * tx + 64 * q]);
#pragma unroll
            for (int a = 0; a < 16; ++a)
#pragma unroll
                for (int c = 0; c < 16; ++c)
                    acc[a][c] = fmaf(za[a], eb[c], acc[a][c]);
        }

        // ---- d = fl( fl(zsq+esq) - 2*dot ); strict < keeps earliest index ----
#pragma unroll
        for (int q = 0; q < 4; ++q) {
            const float esv[4] = {es[q].x, es[q].y, es[q].z, es[q].w};
#pragma unroll
            for (int b = 0; b < 4; ++b) {
                const int k = kb + 64 * q + 4 * tx + b;
                const int c = 4 * q + b;
#pragma unroll
                for (int a = 0; a < 16; ++a) {
                    const float s = zsq_r[a] + esv[b];
                    const float d = fmaf(-2.0f, acc[a][c], s);
                    if (d < best[a]) { best[a] = d; bidx[a] = k; }
                }
            }
        }
    }

    // ---- merge across the 16 tx lanes (first-index ties) ----
#pragma unroll
    for (int off = 1; off < 16; off <<= 1) {
#pragma unroll
        for (int a = 0; a < 16; ++a) {
            const float ov = __shfl_xor(best[a], off, 64);
            const int   oi = __shfl_xor(bidx[a], off, 64);
            if (ov < best[a] || (ov == best[a] && oi < bidx[a])) {
                best[a] = ov; bidx[a] = oi;
            }
        }
    }

    if (tx == 0) {
#pragma unroll
        for (int a = 0; a < 16; ++a) {
            const int t = tb + tg + a;
            pbest[kp * N_TOK + t] = best[a];
            pidx [kp * N_TOK + t] = bidx[a];
        }
    }
}

// ---------------------------------------------------------------------------
// Merge partitions (ascending p + strict < == np first-occurrence), outputs.
// ---------------------------------------------------------------------------
__global__ __launch_bounds__(256) void vq_finish(const float* __restrict__ hid,
                                                 const float* __restrict__ emb,
                                                 const float* __restrict__ pbest,
                                                 const int* __restrict__ pidx,
                                                 float* __restrict__ out_zq,
                                                 float* __restrict__ out_idx,
                                                 float* __restrict__ partials) {
#pragma clang fp contract(off)
    __shared__ float lred[4];
    const int tid = threadIdx.x;
    const int t = blockIdx.x * 256 + tid;

    float best = pbest[t];
    int   bi   = pidx[t];
#pragma unroll
    for (int p = 1; p < KP; ++p) {
        const float b = pbest[p * N_TOK + t];
        const int   i = pidx [p * N_TOK + t];
        if (b < best) { best = b; bi = i; }
    }
    out_idx[t] = (float)bi;

    const float4* q4 = reinterpret_cast<const float4*>(emb + (size_t)bi * DIM);
    const float4* h4 = reinterpret_cast<const float4*>(hid + (size_t)t * DIM);
    float4* o4 = reinterpret_cast<float4*>(out_zq + (size_t)t * DIM);
    float lsum = 0.f;
#pragma unroll
    for (int i = 0; i < 16; ++i) {
        const float4 q = q4[i];
        const float4 h = h4[i];
        float4 zq;
        float dx;
        dx = q.x - h.x; zq.x = h.x + dx; lsum += dx * dx;
        dx = q.y - h.y; zq.y = h.y + dx; lsum += dx * dx;
        dx = q.z - h.z; zq.z = h.z + dx; lsum += dx * dx;
        dx = q.w - h.w; zq.w = h.w + dx; lsum += dx * dx;
        o4[i] = zq;
    }

#pragma unroll
    for (int off = 32; off >= 1; off >>= 1) lsum += __shfl_xor(lsum, off, 64);
    const int wid = tid >> 6;
    if ((tid & 63) == 0) lred[wid] = lsum;
    __syncthreads();
    if (tid == 0) partials[blockIdx.x] = (lred[0] + lred[1]) + (lred[2] + lred[3]);
}

// ---------------------------------------------------------------------------
// Final loss over 128 block partials
// ---------------------------------------------------------------------------
__global__ __launch_bounds__(128) void loss_kernel(const float* __restrict__ partials,
                                                   float* __restrict__ out_loss) {
#pragma clang fp contract(off)
    __shared__ float s[128];
    const int t = threadIdx.x;
    s[t] = partials[t];
    __syncthreads();
    for (int off = 64; off >= 1; off >>= 1) {
        if (t < off) s[t] = s[t] + s[t + off];
        __syncthreads();
    }
    if (t == 0) {
        const float m = s[0] * (1.0f / 2097152.0f);  // exact: /2^21
        out_loss[0] = m + 0.25f * m;
    }
}

extern "C" void kernel_launch(void* const* d_in, const int* in_sizes, int n_in,
                              void* d_out, int out_size, void* d_ws, size_t ws_size,
                              hipStream_t stream) {
    const float* hid = (const float*)d_in[0];
    const float* emb = (const float*)d_in[1];
    float* out = (float*)d_out;
    float* ws  = (float*)d_ws;
    float* esq   = ws + WS_ESQ;
    float* pbest = ws + WS_BEST;
    int*   pidx  = (int*)(ws + WS_PIDX);
    float* parts = ws + WS_PART;

    esq_kernel<<<K_CODES / 32, 256, 0, stream>>>(emb, esq);
    vq_scan<<<TBLK * KP, 256, 0, stream>>>(hid, emb, esq, pbest, pidx);
    vq_finish<<<N_TOK / 256, 256, 0, stream>>>(hid, emb, pbest, pidx,
                                               out, out + IDX_OFF, parts);
    loss_kernel<<<1, 128, 0, stream>>>(parts, out + LOSS_OFF);
}

// Round 5
// 506.714 us; speedup vs baseline: 4.0309x; 1.3114x over previous
//
#include <hip/hip_runtime.h>
#include <cfloat>

#define N_TOK   32768
#define DIM     64
#define K_CODES 8192
#define KP      8                    // K partitions (argmin split, merged with tie-break)
#define KPC     (K_CODES / KP)       // 1024 codes per partition
#define CB      128                  // codes per LDS chunk
#define NCH     (KPC / CB)           // 8 chunks per block
#define TB      256                  // tokens per block
#define TBLK    (N_TOK / TB)         // 128 token blocks

#define IDX_OFF  (N_TOK * DIM)
#define LOSS_OFF (N_TOK * DIM + N_TOK)

// workspace layout (float units)
#define WS_ESQ    0
#define WS_BEST   (WS_ESQ + K_CODES)          // KP * N_TOK floats
#define WS_PIDX   (WS_BEST + KP * N_TOK)      // KP * N_TOK ints
#define WS_PART   (WS_PIDX + KP * N_TOK)      // 128 floats

// ---------------------------------------------------------------------------
// e_sq[k] = numpy-pairwise sum of squares of embedding row k (bitwise np order)
// ---------------------------------------------------------------------------
__global__ __launch_bounds__(256) void esq_kernel(const float* __restrict__ emb,
                                                  float* __restrict__ esq) {
#pragma clang fp contract(off)
    const int tid = threadIdx.x;
    const int q = tid & 7;
    const int code = blockIdx.x * 32 + (tid >> 3);
    const float* row = emb + code * DIM;
    float x = row[q];
    float r = x * x;
#pragma unroll
    for (int m = 1; m < 8; ++m) {
        float y = row[q + 8 * m];
        float sq = y * y;
        r = r + sq;
    }
    r = r + __shfl_xor(r, 1, 64);
    r = r + __shfl_xor(r, 2, 64);
    r = r + __shfl_xor(r, 4, 64);
    if (q == 0) esq[code] = r;
}

// ---------------------------------------------------------------------------
// Distance scan: block = 256 tokens x 1024-code partition (8 chunks of 128).
// 256 threads = 16tx x 16ty; thread tile = 16 tokens x 8 codes; acc = 128 VGPR
// (fits the 256 arch-VGPR cap -> no AGPR shuffling, unlike the 16x16 tile).
// Codes per thread (ascending): {4tx..4tx+3} U {64+4tx..64+4tx+3}.
// ---------------------------------------------------------------------------
__global__ __launch_bounds__(256, 1) void vq_scan(const float* __restrict__ hid,
                                                  const float* __restrict__ emb,
                                                  const float* __restrict__ esq,
                                                  float* __restrict__ pbest,
                                                  int* __restrict__ pidx) {
#pragma clang fp contract(off)
    __shared__ float zT[DIM][TB];     // zT[j][t]   (reads: 4 distinct 64B -> clean)
    __shared__ float eT[DIM][CB];     // eT[j][c]   (reads: 2-way -> free)
    __shared__ float zsq_s[TB];

    const int tid = threadIdx.x;
    const int bid = blockIdx.x;
    const int kp  = bid >> 7;                 // partition
    const int tb  = (bid & (TBLK - 1)) * TB;  // token base
    const int k0  = kp * KPC;

    const int tx = tid & 15;        // code lane
    const int ty = tid >> 4;        // token group
    const int tg = ty * 16;         // 16 tokens per thread

    // ---- stage z tile (thread = one token row) + z_sq (numpy pairwise) ----
    {
        const float4* h4 = reinterpret_cast<const float4*>(hid + (size_t)(tb + tid) * DIM);
        float4 v[16];
#pragma unroll
        for (int i = 0; i < 16; ++i) v[i] = h4[i];
#pragma unroll
        for (int i = 0; i < 16; ++i) {
            const int j = 4 * i;
            zT[j + 0][tid] = v[i].x;
            zT[j + 1][tid] = v[i].y;
            zT[j + 2][tid] = v[i].z;
            zT[j + 3][tid] = v[i].w;
        }
        const float* zr = reinterpret_cast<const float*>(v);
        float r[8];
#pragma unroll
        for (int q = 0; q < 8; ++q) {
            float x = zr[q];
            r[q] = x * x;
#pragma unroll
            for (int m = 1; m < 8; ++m) {
                float y = zr[q + 8 * m];
                float sq = y * y;
                r[q] = r[q] + sq;
            }
        }
        zsq_s[tid] = ((r[0] + r[1]) + (r[2] + r[3])) + ((r[4] + r[5]) + (r[6] + r[7]));
    }
    __syncthreads();

    float zsq_r[16];
#pragma unroll
    for (int a = 0; a < 4; ++a)
        *reinterpret_cast<float4*>(&zsq_r[4 * a]) =
            *reinterpret_cast<const float4*>(&zsq_s[tg + 4 * a]);

    float best[16];
    int   bidx[16];
#pragma unroll
    for (int a = 0; a < 16; ++a) { best[a] = FLT_MAX; bidx[a] = 0; }

    for (int ch = 0; ch < NCH; ++ch) {
        if (ch) __syncthreads();            // eT overwrite guard
        // ---- stage e chunk: thread = half a code row (32 floats) ----
        {
            const int  c     = tid >> 1;            // code row 0..127
            const int  jh    = (tid & 1) * 32;      // j half
            const float4* e4 = reinterpret_cast<const float4*>(
                emb + (size_t)(k0 + ch * CB + c) * DIM + jh);
            float4 v[8];
#pragma unroll
            for (int i = 0; i < 8; ++i) v[i] = e4[i];
#pragma unroll
            for (int i = 0; i < 8; ++i) {
                const int j = jh + 4 * i;
                eT[j + 0][c] = v[i].x;
                eT[j + 1][c] = v[i].y;
                eT[j + 2][c] = v[i].z;
                eT[j + 3][c] = v[i].w;
            }
        }
        __syncthreads();

        const int kb = k0 + ch * CB;
        float4 es0 = *reinterpret_cast<const float4*>(esq + kb + 4 * tx);
        float4 es1 = *reinterpret_cast<const float4*>(esq + kb + 64 + 4 * tx);

        float acc[16][8];

        // ---- j = 0 peeled: acc = z0 * e0 (bitwise head of BLAS chain) ----
        {
            float za[16], eb[8];
#pragma unroll
            for (int a = 0; a < 4; ++a)
                *reinterpret_cast<float4*>(&za[4 * a]) =
                    *reinterpret_cast<const float4*>(&zT[0][tg + 4 * a]);
            *reinterpret_cast<float4*>(&eb[0]) =
                *reinterpret_cast<const float4*>(&eT[0][4 * tx]);
            *reinterpret_cast<float4*>(&eb[4]) =
                *reinterpret_cast<const float4*>(&eT[0][64 + 4 * tx]);
#pragma unroll
            for (int a = 0; a < 16; ++a)
#pragma unroll
                for (int c = 0; c < 8; ++c)
                    acc[a][c] = za[a] * eb[c];
        }

        // ---- j = 1..63: sequential FMA chains ----
#pragma unroll 4
        for (int j = 1; j < DIM; ++j) {
            float za[16], eb[8];
#pragma unroll
            for (int a = 0; a < 4; ++a)
                *reinterpret_cast<float4*>(&za[4 * a]) =
                    *reinterpret_cast<const float4*>(&zT[j][tg + 4 * a]);
            *reinterpret_cast<float4*>(&eb[0]) =
                *reinterpret_cast<const float4*>(&eT[j][4 * tx]);
            *reinterpret_cast<float4*>(&eb[4]) =
                *reinterpret_cast<const float4*>(&eT[j][64 + 4 * tx]);
#pragma unroll
            for (int a = 0; a < 16; ++a)
#pragma unroll
                for (int c = 0; c < 8; ++c)
                    acc[a][c] = fmaf(za[a], eb[c], acc[a][c]);
        }

        // ---- d = fl( fl(zsq+esq) - 2*dot ); strict < keeps earliest index ----
#pragma unroll
        for (int q = 0; q < 2; ++q) {
            const float4 es = q ? es1 : es0;
            const float esv[4] = {es.x, es.y, es.z, es.w};
#pragma unroll
            for (int b = 0; b < 4; ++b) {
                const int k = kb + 64 * q + 4 * tx + b;
                const int c = 4 * q + b;
#pragma unroll
                for (int a = 0; a < 16; ++a) {
                    const float s = zsq_r[a] + esv[b];
                    const float d = fmaf(-2.0f, acc[a][c], s);
                    if (d < best[a]) { best[a] = d; bidx[a] = k; }
                }
            }
        }
    }

    // ---- merge across the 16 tx lanes (first-index ties) ----
#pragma unroll
    for (int off = 1; off < 16; off <<= 1) {
#pragma unroll
        for (int a = 0; a < 16; ++a) {
            const float ov = __shfl_xor(best[a], off, 64);
            const int   oi = __shfl_xor(bidx[a], off, 64);
            if (ov < best[a] || (ov == best[a] && oi < bidx[a])) {
                best[a] = ov; bidx[a] = oi;
            }
        }
    }

    if (tx == 0) {
#pragma unroll
        for (int a = 0; a < 16; ++a) {
            const int t = tb + tg + a;
            pbest[kp * N_TOK + t] = best[a];
            pidx [kp * N_TOK + t] = bidx[a];
        }
    }
}

// ---------------------------------------------------------------------------
// Merge partitions (ascending p + strict < == np first-occurrence), outputs.
// ---------------------------------------------------------------------------
__global__ __launch_bounds__(256) void vq_finish(const float* __restrict__ hid,
                                                 const float* __restrict__ emb,
                                                 const float* __restrict__ pbest,
                                                 const int* __restrict__ pidx,
                                                 float* __restrict__ out_zq,
                                                 float* __restrict__ out_idx,
                                                 float* __restrict__ partials) {
#pragma clang fp contract(off)
    __shared__ float lred[4];
    const int tid = threadIdx.x;
    const int t = blockIdx.x * 256 + tid;

    float best = pbest[t];
    int   bi   = pidx[t];
#pragma unroll
    for (int p = 1; p < KP; ++p) {
        const float b = pbest[p * N_TOK + t];
        const int   i = pidx [p * N_TOK + t];
        if (b < best) { best = b; bi = i; }
    }
    out_idx[t] = (float)bi;

    const float4* q4 = reinterpret_cast<const float4*>(emb + (size_t)bi * DIM);
    const float4* h4 = reinterpret_cast<const float4*>(hid + (size_t)t * DIM);
    float4* o4 = reinterpret_cast<float4*>(out_zq + (size_t)t * DIM);
    float lsum = 0.f;
#pragma unroll
    for (int i = 0; i < 16; ++i) {
        const float4 q = q4[i];
        const float4 h = h4[i];
        float4 zq;
        float dx;
        dx = q.x - h.x; zq.x = h.x + dx; lsum += dx * dx;
        dx = q.y - h.y; zq.y = h.y + dx; lsum += dx * dx;
        dx = q.z - h.z; zq.z = h.z + dx; lsum += dx * dx;
        dx = q.w - h.w; zq.w = h.w + dx; lsum += dx * dx;
        o4[i] = zq;
    }

#pragma unroll
    for (int off = 32; off >= 1; off >>= 1) lsum += __shfl_xor(lsum, off, 64);
    const int wid = tid >> 6;
    if ((tid & 63) == 0) lred[wid] = lsum;
    __syncthreads();
    if (tid == 0) partials[blockIdx.x] = (lred[0] + lred[1]) + (lred[2] + lred[3]);
}

// ---------------------------------------------------------------------------
// Final loss over 128 block partials
// ---------------------------------------------------------------------------
__global__ __launch_bounds__(128) void loss_kernel(const float* __restrict__ partials,
                                                   float* __restrict__ out_loss) {
#pragma clang fp contract(off)
    __shared__ float s[128];
    const int t = threadIdx.x;
    s[t] = partials[t];
    __syncthreads();
    for (int off = 64; off >= 1; off >>= 1) {
        if (t < off) s[t] = s[t] + s[t + off];
        __syncthreads();
    }
    if (t == 0) {
        const float m = s[0] * (1.0f / 2097152.0f);  // exact: /2^21
        out_loss[0] = m + 0.25f * m;
    }
}

extern "C" void kernel_launch(void* const* d_in, const int* in_sizes, int n_in,
                              void* d_out, int out_size, void* d_ws, size_t ws_size,
                              hipStream_t stream) {
    const float* hid = (const float*)d_in[0];
    const float* emb = (const float*)d_in[1];
    float* out = (float*)d_out;
    float* ws  = (float*)d_ws;
    float* esq   = ws + WS_ESQ;
    float* pbest = ws + WS_BEST;
    int*   pidx  = (int*)(ws + WS_PIDX);
    float* parts = ws + WS_PART;

    esq_kernel<<<K_CODES / 32, 256, 0, stream>>>(emb, esq);
    vq_scan<<<TBLK * KP, 256, 0, stream>>>(hid, emb, esq, pbest, pidx);
    vq_finish<<<N_TOK / 256, 256, 0, stream>>>(hid, emb, pbest, pidx,
                                               out, out + IDX_OFF, parts);
    loss_kernel<<<1, 128, 0, stream>>>(parts, out + LOSS_OFF);
}

// Round 6
// 425.730 us; speedup vs baseline: 4.7977x; 1.1902x over previous
//
#include <hip/hip_runtime.h>
#include <cfloat>

#define N_TOK   32768
#define DIM     64
#define K_CODES 8192
#define KP      8                    // K partitions (argmin split, merged with tie-break)
#define KPC     (K_CODES / KP)       // 1024 codes per partition
#define CB      128                  // codes per LDS chunk
#define NCH     (KPC / CB)           // 8 chunks per partition
#define TB      128                  // tokens per block
#define TBLK    (N_TOK / TB)         // 256 token blocks
#define LS      132                  // LDS row stride (2-way banks, 16B aligned)

#define IDX_OFF  (N_TOK * DIM)
#define LOSS_OFF (N_TOK * DIM + N_TOK)

// workspace layout (float units)
#define WS_ESQ    0
#define WS_BEST   (WS_ESQ + K_CODES)          // KP * N_TOK floats
#define WS_PIDX   (WS_BEST + KP * N_TOK)      // KP * N_TOK ints
#define WS_PART   (WS_PIDX + KP * N_TOK)      // 128 floats

// ---------------------------------------------------------------------------
// e_sq[k] = numpy-pairwise sum of squares of embedding row k (bitwise np order)
// ---------------------------------------------------------------------------
__global__ __launch_bounds__(256) void esq_kernel(const float* __restrict__ emb,
                                                  float* __restrict__ esq) {
#pragma clang fp contract(off)
    const int tid = threadIdx.x;
    const int q = tid & 7;
    const int code = blockIdx.x * 32 + (tid >> 3);
    const float* row = emb + code * DIM;
    float x = row[q];
    float r = x * x;
#pragma unroll
    for (int m = 1; m < 8; ++m) {
        float y = row[q + 8 * m];
        float sq = y * y;
        r = r + sq;
    }
    r = r + __shfl_xor(r, 1, 64);
    r = r + __shfl_xor(r, 2, 64);
    r = r + __shfl_xor(r, 4, 64);
    if (q == 0) esq[code] = r;
}

// ---------------------------------------------------------------------------
// Distance scan (R2-proven structure + K-partitioning for 2 blocks/CU):
// block = 128 tokens x 1024-code partition (8 chunks of 128 codes).
// 16tx x 16ty threads, thread tile = 8 tokens x 8 codes (VGPR ~96).
// Thread's codes (ascending): {4tx..4tx+3} U {64+4tx..64+4tx+3}.
// LDS 68 KB -> 2 blocks resident per CU -> barriers/staging overlap compute.
// ---------------------------------------------------------------------------
__global__ __launch_bounds__(256, 2) void vq_scan(const float* __restrict__ hid,
                                                  const float* __restrict__ emb,
                                                  const float* __restrict__ esq,
                                                  float* __restrict__ pbest,
                                                  int* __restrict__ pidx) {
#pragma clang fp contract(off)
    __shared__ float zT[DIM][LS];     // zT[j][t], t in [0,128)
    __shared__ float eT[DIM][LS];     // eT[j][c], c in [0,128)
    __shared__ float zsq_s[TB];

    const int tid = threadIdx.x;
    const int bid = blockIdx.x;
    const int kp  = bid >> 8;                 // partition 0..7
    const int tb  = (bid & (TBLK - 1)) * TB;  // token base
    const int k0  = kp * KPC;

    // ---- stage z tile, transposed (32 floats per thread) ----
    {
        const int tr = tid >> 1;            // token row 0..127
        const int tj0 = (tid & 1) * 32;     // j-range start
        const float4* h4 = reinterpret_cast<const float4*>(hid + (size_t)(tb + tr) * DIM + tj0);
        float4 v[8];
#pragma unroll
        for (int i = 0; i < 8; ++i) v[i] = h4[i];
#pragma unroll
        for (int i = 0; i < 8; ++i) {
            const int j = tj0 + 4 * i;
            zT[j + 0][tr] = v[i].x;
            zT[j + 1][tr] = v[i].y;
            zT[j + 2][tr] = v[i].z;
            zT[j + 3][tr] = v[i].w;
        }
    }
    __syncthreads();

    // ---- z_sq per token, numpy pairwise order (threads 0..127) ----
    if (tid < TB) {
        const int t = tid;
        float r[8];
#pragma unroll
        for (int q = 0; q < 8; ++q) {
            float x = zT[q][t];
            r[q] = x * x;
#pragma unroll
            for (int m = 1; m < 8; ++m) {
                float y = zT[q + 8 * m][t];
                float sq = y * y;
                r[q] = r[q] + sq;
            }
        }
        const float s01 = r[0] + r[1], s23 = r[2] + r[3];
        const float s45 = r[4] + r[5], s67 = r[6] + r[7];
        zsq_s[t] = (s01 + s23) + (s45 + s67);
    }

    const int tx = tid & 15;        // code lane
    const int ty = tid >> 4;        // token group
    const int tg = ty * 8;          // 8 tokens per thread
    const int cg = tx * 4;          // first code quad; second at cg+64

    // prefetch chunk 0 into registers (global->reg->LDS pipeline)
    const int pc  = tid >> 1;            // code row 0..127 within chunk
    const int pj0 = (tid & 1) * 32;
    float4 pref[8];
    {
        const float4* e4 = reinterpret_cast<const float4*>(
            emb + (size_t)(k0 + pc) * DIM + pj0);
#pragma unroll
        for (int i = 0; i < 8; ++i) pref[i] = e4[i];
    }
    __syncthreads();                // zsq_s ready

    float zsq_r[8];
#pragma unroll
    for (int a = 0; a < 8; ++a) zsq_r[a] = zsq_s[tg + a];

    float best[8];
    int   bidx[8];
#pragma unroll
    for (int a = 0; a < 8; ++a) { best[a] = FLT_MAX; bidx[a] = 0; }

    for (int ch = 0; ch < NCH; ++ch) {
        // write prefetched chunk to LDS (transposed)
#pragma unroll
        for (int i = 0; i < 8; ++i) {
            const int j = pj0 + 4 * i;
            eT[j + 0][pc] = pref[i].x;
            eT[j + 1][pc] = pref[i].y;
            eT[j + 2][pc] = pref[i].z;
            eT[j + 3][pc] = pref[i].w;
        }
        __syncthreads();

        // prefetch next chunk (hides under compute below)
        if (ch + 1 < NCH) {
            const float4* e4 = reinterpret_cast<const float4*>(
                emb + (size_t)(k0 + (ch + 1) * CB + pc) * DIM + pj0);
#pragma unroll
            for (int i = 0; i < 8; ++i) pref[i] = e4[i];
        }

        const int kb = k0 + ch * CB;
        const float4 es0 = *reinterpret_cast<const float4*>(esq + kb + cg);
        const float4 es1 = *reinterpret_cast<const float4*>(esq + kb + 64 + cg);

        float acc[8][8];
#pragma unroll
        for (int a = 0; a < 8; ++a)
#pragma unroll
            for (int b = 0; b < 8; ++b) acc[a][b] = 0.f;

        // sequential-j FMA chains: bitwise-matches BLAS k-sequential accumulation
#pragma unroll 8
        for (int j = 0; j < DIM; ++j) {
            const float4 zv0 = *reinterpret_cast<const float4*>(&zT[j][tg]);
            const float4 zv1 = *reinterpret_cast<const float4*>(&zT[j][tg + 4]);
            const float4 ev0 = *reinterpret_cast<const float4*>(&eT[j][cg]);
            const float4 ev1 = *reinterpret_cast<const float4*>(&eT[j][cg + 64]);
            const float za[8] = {zv0.x, zv0.y, zv0.z, zv0.w, zv1.x, zv1.y, zv1.z, zv1.w};
            const float eb[8] = {ev0.x, ev0.y, ev0.z, ev0.w, ev1.x, ev1.y, ev1.z, ev1.w};
#pragma unroll
            for (int a = 0; a < 8; ++a)
#pragma unroll
                for (int b = 0; b < 8; ++b)
                    acc[a][b] = fmaf(za[a], eb[b], acc[a][b]);
        }

        // d = fl( fl(z_sq + e_sq) - 2*dot ); strict < keeps earliest index
        const float esv[8] = {es0.x, es0.y, es0.z, es0.w, es1.x, es1.y, es1.z, es1.w};
#pragma unroll
        for (int b = 0; b < 8; ++b) {
            const int k = kb + ((b < 4) ? (cg + b) : (64 + cg + (b - 4)));
#pragma unroll
            for (int a = 0; a < 8; ++a) {
                const float s = zsq_r[a] + esv[b];
                const float d = fmaf(-2.0f, acc[a][b], s);
                if (d < best[a]) { best[a] = d; bidx[a] = k; }
            }
        }
        __syncthreads();
    }

    // ---- combine across the 16 lanes sharing a token group (first-index ties) ----
#pragma unroll
    for (int off = 1; off < 16; off <<= 1) {
#pragma unroll
        for (int a = 0; a < 8; ++a) {
            const float ov = __shfl_xor(best[a], off, 64);
            const int   oi = __shfl_xor(bidx[a], off, 64);
            if (ov < best[a] || (ov == best[a] && oi < bidx[a])) {
                best[a] = ov; bidx[a] = oi;
            }
        }
    }

    if (tx == 0) {
#pragma unroll
        for (int a = 0; a < 8; ++a) {
            const int t = tb + tg + a;
            pbest[kp * N_TOK + t] = best[a];
            pidx [kp * N_TOK + t] = bidx[a];
        }
    }
}

// ---------------------------------------------------------------------------
// Merge partitions (ascending p + strict < == np first-occurrence), outputs.
// ---------------------------------------------------------------------------
__global__ __launch_bounds__(256) void vq_finish(const float* __restrict__ hid,
                                                 const float* __restrict__ emb,
                                                 const float* __restrict__ pbest,
                                                 const int* __restrict__ pidx,
                                                 float* __restrict__ out_zq,
                                                 float* __restrict__ out_idx,
                                                 float* __restrict__ partials) {
#pragma clang fp contract(off)
    __shared__ float lred[4];
    const int tid = threadIdx.x;
    const int t = blockIdx.x * 256 + tid;

    float best = pbest[t];
    int   bi   = pidx[t];
#pragma unroll
    for (int p = 1; p < KP; ++p) {
        const float b = pbest[p * N_TOK + t];
        const int   i = pidx [p * N_TOK + t];
        if (b < best) { best = b; bi = i; }
    }
    out_idx[t] = (float)bi;

    const float4* q4 = reinterpret_cast<const float4*>(emb + (size_t)bi * DIM);
    const float4* h4 = reinterpret_cast<const float4*>(hid + (size_t)t * DIM);
    float4* o4 = reinterpret_cast<float4*>(out_zq + (size_t)t * DIM);
    float lsum = 0.f;
#pragma unroll
    for (int i = 0; i < 16; ++i) {
        const float4 q = q4[i];
        const float4 h = h4[i];
        float4 zq;
        float dx;
        dx = q.x - h.x; zq.x = h.x + dx; lsum += dx * dx;
        dx = q.y - h.y; zq.y = h.y + dx; lsum += dx * dx;
        dx = q.z - h.z; zq.z = h.z + dx; lsum += dx * dx;
        dx = q.w - h.w; zq.w = h.w + dx; lsum += dx * dx;
        o4[i] = zq;
    }

#pragma unroll
    for (int off = 32; off >= 1; off >>= 1) lsum += __shfl_xor(lsum, off, 64);
    const int wid = tid >> 6;
    if ((tid & 63) == 0) lred[wid] = lsum;
    __syncthreads();
    if (tid == 0) partials[blockIdx.x] = (lred[0] + lred[1]) + (lred[2] + lred[3]);
}

// ---------------------------------------------------------------------------
// Final loss over 128 block partials
// ---------------------------------------------------------------------------
__global__ __launch_bounds__(128) void loss_kernel(const float* __restrict__ partials,
                                                   float* __restrict__ out_loss) {
#pragma clang fp contract(off)
    __shared__ float s[128];
    const int t = threadIdx.x;
    s[t] = partials[t];
    __syncthreads();
    for (int off = 64; off >= 1; off >>= 1) {
        if (t < off) s[t] = s[t] + s[t + off];
        __syncthreads();
    }
    if (t == 0) {
        const float m = s[0] * (1.0f / 2097152.0f);  // exact: /2^21
        out_loss[0] = m + 0.25f * m;
    }
}

extern "C" void kernel_launch(void* const* d_in, const int* in_sizes, int n_in,
                              void* d_out, int out_size, void* d_ws, size_t ws_size,
                              hipStream_t stream) {
    const float* hid = (const float*)d_in[0];
    const float* emb = (const float*)d_in[1];
    float* out = (float*)d_out;
    float* ws  = (float*)d_ws;
    float* esq   = ws + WS_ESQ;
    float* pbest = ws + WS_BEST;
    int*   pidx  = (int*)(ws + WS_PIDX);
    float* parts = ws + WS_PART;

    esq_kernel<<<K_CODES / 32, 256, 0, stream>>>(emb, esq);
    vq_scan<<<TBLK * KP, 256, 0, stream>>>(hid, emb, esq, pbest, pidx);
    vq_finish<<<N_TOK / 256, 256, 0, stream>>>(hid, emb, pbest, pidx,
                                               out, out + IDX_OFF, parts);
    loss_kernel<<<1, 128, 0, stream>>>(parts, out + LOSS_OFF);
}